// Round 1
// baseline (409.111 us; speedup 1.0000x reference)
//
#include <hip/hip_runtime.h>

// ---------------------------------------------------------------------------
// Fused MHA block on MI355X (gfx950). fp16 MFMA 16x16x32, fp32 accum.
// Round-8:
//  * gemm_nt rewritten as 8-phase-style pipelined GEMM (T1+T3+T4+T5):
//    256x128 tile, BK=64, 512 thr (8 waves, 4Mx2N, 64x64/wave), LDS 96 KiB
//    double-buffered. 4 phases per K-tile, each phase:
//      {4x ds_read_b128 | issue 1 half-tile global_load_lds} -> s_barrier ->
//      lgkmcnt(0) -> setprio(1) 8xMFMA setprio(0) -> s_barrier
//    Counted vmcnt per phase (3/4/3/2) -- never 0 in the main loop; prefetch
//    stays in flight across barriers. One MFMA quadrant (mt23 x nt23) is
//    deferred to the next tile's phase 0 so all phases carry 8 MFMAs.
//    Grid is exactly round for both GEMMs: QKV 48x16=768 blocks (3 full CU
//    rounds), WO 16x16=256 (1 round). Bijective XCD swizzle, bm-fastest.
//  * flash_attn / cvt_all unchanged from round-7 (verified).
// ---------------------------------------------------------------------------

typedef _Float16 half8 __attribute__((ext_vector_type(8)));
typedef _Float16 half4 __attribute__((ext_vector_type(4)));
typedef float floatx4 __attribute__((ext_vector_type(4)));

__device__ __forceinline__ void async16(const void* g, void* l) {
  __builtin_amdgcn_global_load_lds((__attribute__((address_space(1))) void*)(g),
                                   (__attribute__((address_space(3))) void*)(l),
                                   16, 0, 0);
}

// ---- fp32 -> fp16 convert: x (2^21 quads) then 4 weights (2^20 each) -------
__global__ void cvt_all(const float* __restrict__ x, const float* __restrict__ w0,
                        const float* __restrict__ w1, const float* __restrict__ w2,
                        const float* __restrict__ w3, _Float16* __restrict__ xh,
                        _Float16* __restrict__ wh, float scale0) {
  int i = blockIdx.x * blockDim.x + threadIdx.x;
  const int XQ = 1 << 21;
  float sc = 1.0f;
  const float* src;
  _Float16* dst;
  int j;
  if (i < XQ) { src = x; dst = xh; j = i; }
  else {
    int t = i - XQ;
    int m = t >> 20;
    src = (m == 0) ? w0 : (m == 1) ? w1 : (m == 2) ? w2 : w3;
    if (m == 0) sc = scale0;
    dst = wh; j = t;
  }
  int js = (i < XQ) ? j : (j & ((1 << 20) - 1));
  float4 v = reinterpret_cast<const float4*>(src)[js];
  union { _Float16 h[4]; short4 s; } u;
  u.h[0] = (_Float16)(v.x * sc); u.h[1] = (_Float16)(v.y * sc);
  u.h[2] = (_Float16)(v.z * sc); u.h[3] = (_Float16)(v.w * sc);
  reinterpret_cast<short4*>(dst)[j] = u.s;
}

// ---- pipelined NT GEMM helpers ---------------------------------------------
template <int MO, int NO>
__device__ __forceinline__ void mmg(floatx4 (&acc)[4][4], const half8 (&af)[2][2],
                                    const half8 (&bf)[2][2]) {
#pragma unroll
  for (int mt = 0; mt < 2; ++mt)
#pragma unroll
    for (int nt = 0; nt < 2; ++nt)
#pragma unroll
      for (int ks = 0; ks < 2; ++ks)
        acc[MO + mt][NO + nt] = __builtin_amdgcn_mfma_f32_16x16x32_f16(
            af[mt][ks], bf[nt][ks], acc[MO + mt][NO + nt], 0, 0, 0);
}

__device__ __forceinline__ void rdfrag(half8 (&f)[2][2], const _Float16* base,
                                       int r0, int r1, int ch0, int ch1) {
  f[0][0] = *reinterpret_cast<const half8*>(base + r0 * 64 + ch0);
  f[0][1] = *reinterpret_cast<const half8*>(base + r0 * 64 + ch1);
  f[1][0] = *reinterpret_cast<const half8*>(base + r1 * 64 + ch0);
  f[1][1] = *reinterpret_cast<const half8*>(base + r1 * 64 + ch1);
}

// ---- NT GEMM (16x16x32): C[m][n] = sum_k A[m][k]*Bw[n][k] ------------------
// 256x128 tile, 512 threads. OUT_MODE 0: fused QKV epilogue (Q/K row-major
// fp16, V per-batch transposed). OUT_MODE 2: fp32 row-major.
template <int OUT_MODE>
__global__ __launch_bounds__(512, 2)
void gemm_nt(const _Float16* __restrict__ A, const _Float16* __restrict__ Bw,
             void* __restrict__ Cv, void* __restrict__ Cv2) {
  __shared__ _Float16 As[2][256 * 64];   // A tile: rows 0-127 = Ah0, 128-255 = Ah1
  __shared__ _Float16 Bs[2][128 * 64];   // B tile: rows 0-63 = Bh0, 64-127 = Bh1
  const int tid = threadIdx.x;
  const int wave = tid >> 6, lane = tid & 63;
  const int wm = wave >> 1, wn = wave & 1;      // 4M x 2N wave grid
  const int l15 = lane & 15, l4 = lane >> 4;

  // XCD-aware bijective swizzle; bm fastest so each XCD keeps B panels hot.
  // nwg = gridDim.x*16 is a multiple of 8 for both launches (768 / 256).
  const int nwg = gridDim.x << 4;
  const int orig = blockIdx.x * 16 + blockIdx.y;
  const int swz = (orig & 7) * (nwg >> 3) + (orig >> 3);
  const int bm = swz & 15, bn = swz >> 4;

  // Staging addresses. A: 4 loads/thread (2 per half); B: 2 (1 per half).
  // xor-swizzled global source, linear LDS dest (both-sides-or-neither rule).
  const _Float16* ag[4]; int al[4];
#pragma unroll
  for (int j = 0; j < 4; ++j) {
    int c = j * 512 + tid, row = c >> 3, g = (c & 7) ^ (row & 7);
    ag[j] = A + (size_t)(bm * 256 + row) * 2048 + g * 8;
    al[j] = c * 8;
  }
  const _Float16* bg[2]; int bl[2];
#pragma unroll
  for (int j = 0; j < 2; ++j) {
    int c = j * 512 + tid, row = c >> 3, g = (c & 7) ^ (row & 7);
    bg[j] = Bw + (size_t)(bn * 128 + row) * 2048 + g * 8;
    bl[j] = c * 8;
  }

  // Fragment read coords. A rows: mt*64 + wm*16 + l15 (mt01 in Ah0, mt23 Ah1);
  // B rows: nt*32 + wn*16 + l15 (nt01 in Bh0, nt23 in Bh1). row&7 == l15&7.
  const int rm = wm * 16 + l15;
  const int rn = wn * 16 + l15;
  const int ch0 = (l4 ^ (l15 & 7)) * 8;
  const int ch1 = ((l4 + 4) ^ (l15 & 7)) * 8;

  // Prologue: stage tile 0, one-time full drain.
#pragma unroll
  for (int j = 0; j < 4; ++j) async16(ag[j], &As[0][al[j]]);
#pragma unroll
  for (int j = 0; j < 2; ++j) async16(bg[j], &Bs[0][bl[j]]);
  asm volatile("s_waitcnt vmcnt(0)" ::: "memory");
  __builtin_amdgcn_s_barrier();

  floatx4 acc[4][4] = {};
  half8 afA[2][2], afB[2][2], bfA[2][2], bfB[2][2];

#pragma unroll 2
  for (int t = 0; t < 32; ++t) {
    const _Float16* Ac = &As[t & 1][0];
    const _Float16* Bc = &Bs[t & 1][0];
    _Float16* An = &As[(t & 1) ^ 1][0];
    _Float16* Bn = &Bs[(t & 1) ^ 1][0];
    const int kn = t * 64 + 64;
    const bool st = (t < 31);

    // -- phase 0: read afA (Ah0[t]); stage Ah0[t+1]; MFMA leftover q(2,2) t-1
    asm volatile("s_waitcnt vmcnt(3)" ::: "memory");
    rdfrag(afA, Ac, rm, rm + 64, ch0, ch1);
    if (st) { async16(ag[0] + kn, An + al[0]); async16(ag[1] + kn, An + al[1]); }
    __builtin_amdgcn_s_barrier();
    __builtin_amdgcn_s_waitcnt(0xC07F);   // lgkmcnt(0)
    __builtin_amdgcn_s_setprio(1);
    if (t) mmg<2, 2>(acc, afB, bfB);
    __builtin_amdgcn_s_setprio(0);
    __builtin_amdgcn_s_barrier();

    // -- phase 1: read bfA (Bh0[t]); stage Bh0[t+1]; MFMA q(0,0)
    asm volatile("s_waitcnt vmcnt(4)" ::: "memory");
    rdfrag(bfA, Bc, rn, rn + 32, ch0, ch1);
    if (st) async16(bg[0] + kn, Bn + bl[0]);
    __builtin_amdgcn_s_barrier();
    __builtin_amdgcn_s_waitcnt(0xC07F);
    __builtin_amdgcn_s_setprio(1);
    mmg<0, 0>(acc, afA, bfA);
    __builtin_amdgcn_s_setprio(0);
    __builtin_amdgcn_s_barrier();

    // -- phase 2: read bfB (Bh1[t]); stage Bh1[t+1]; MFMA q(0,2)
    asm volatile("s_waitcnt vmcnt(3)" ::: "memory");
    rdfrag(bfB, Bc, rn + 64, rn + 96, ch0, ch1);
    if (st) async16(bg[1] + kn, Bn + bl[1]);
    __builtin_amdgcn_s_barrier();
    __builtin_amdgcn_s_waitcnt(0xC07F);
    __builtin_amdgcn_s_setprio(1);
    mmg<0, 2>(acc, afA, bfB);
    __builtin_amdgcn_s_setprio(0);
    __builtin_amdgcn_s_barrier();

    // -- phase 3: read afB (Ah1[t]); stage Ah1[t+1]; MFMA q(2,0)
    asm volatile("s_waitcnt vmcnt(2)" ::: "memory");
    rdfrag(afB, Ac, rm + 128, rm + 192, ch0, ch1);
    if (st) { async16(ag[2] + kn, An + al[2]); async16(ag[3] + kn, An + al[3]); }
    __builtin_amdgcn_s_barrier();
    __builtin_amdgcn_s_waitcnt(0xC07F);
    __builtin_amdgcn_s_setprio(1);
    mmg<2, 0>(acc, afB, bfA);
    __builtin_amdgcn_s_setprio(0);
    __builtin_amdgcn_s_barrier();
  }
  mmg<2, 2>(acc, afB, bfB);   // leftover quadrant of the last tile

  // ---- epilogues (frag coords: row = bm*256+mt*64+wm*16+l4*4+r,
  //                  col = bn*128+nt*32+wn*16+l15) ----
  const int cb = bn * 128;
  if constexpr (OUT_MODE == 0) {
    if (cb < 4096) {            // Q or K: row-major fp16, ld 2048
      _Float16* C = (_Float16*)Cv + (size_t)(cb >> 11) * (4096ull * 2048);
#pragma unroll
      for (int mt = 0; mt < 4; ++mt)
#pragma unroll
        for (int nt = 0; nt < 4; ++nt) {
          int r0 = bm * 256 + mt * 64 + wm * 16 + l4 * 4;
          int cg = (cb + nt * 32 + wn * 16 + l15) & 2047;
#pragma unroll
          for (int r = 0; r < 4; ++r)
            C[(size_t)(r0 + r) * 2048 + cg] = (_Float16)acc[mt][nt][r];
        }
    } else {                    // V: per-batch transposed [b][d][s]
      _Float16* C = (_Float16*)Cv2;
#pragma unroll
      for (int mt = 0; mt < 4; ++mt)
#pragma unroll
        for (int nt = 0; nt < 4; ++nt) {
          int m0 = bm * 256 + mt * 64 + wm * 16 + l4 * 4;
          int d = cb + nt * 32 + wn * 16 + l15 - 4096;
          size_t base = (size_t)(m0 >> 11) * (2048ull * 2048) + (size_t)d * 2048 + (m0 & 2047);
          union { _Float16 h[4]; short4 s; } u;
#pragma unroll
          for (int r = 0; r < 4; ++r) u.h[r] = (_Float16)acc[mt][nt][r];
          *reinterpret_cast<short4*>(C + base) = u.s;
        }
    }
  } else {
    float* C = (float*)Cv;
#pragma unroll
    for (int mt = 0; mt < 4; ++mt)
#pragma unroll
      for (int nt = 0; nt < 4; ++nt) {
        int r0 = bm * 256 + mt * 64 + wm * 16 + l4 * 4;
        int cg = cb + nt * 32 + wn * 16 + l15;
#pragma unroll
        for (int r = 0; r < 4; ++r)
          C[(size_t)(r0 + r) * 2048 + cg] = acc[mt][nt][r];
      }
  }
}

// ---- Flash attention (unchanged, round-7 verified) --------------------------
// grid = (16 q-tiles of 128, 32 b*h); block = 256 (4 waves x 32 q rows).
__global__ __launch_bounds__(256, 2)
void flash_attn(const _Float16* __restrict__ Q, const _Float16* __restrict__ Kg,
                const _Float16* __restrict__ Vt, _Float16* __restrict__ O) {
  __shared__ _Float16 Ks[64 * 128];   // [key][hd], 16-chunk xor swizzle
  __shared__ _Float16 Vs[128 * 64];   // [d][s],    8-chunk xor swizzle
  __shared__ _Float16 Ps[128 * 64];   // [q][key],  8-chunk xor swizzle
  const int tid = threadIdx.x, wave = tid >> 6, lane = tid & 63;
  const int l15 = lane & 15, l4 = lane >> 4;
  const int bh = blockIdx.y, b = bh >> 4, h = bh & 15;
  const int q0 = blockIdx.x * 128;

  const _Float16* Qp = Q + ((size_t)(b * 2048 + q0 + wave * 32)) * 2048 + h * 128;
  const _Float16* Kp = Kg + (size_t)b * 2048 * 2048 + h * 128;
  const _Float16* Vp = Vt + (size_t)b * 2048 * 2048 + (size_t)(h * 128) * 2048;

  half8 qf[2][4];
#pragma unroll
  for (int qt = 0; qt < 2; ++qt)
#pragma unroll
    for (int ks = 0; ks < 4; ++ks)
      qf[qt][ks] = *reinterpret_cast<const half8*>(
          Qp + (size_t)(qt * 16 + l15) * 2048 + ks * 32 + l4 * 8);

  floatx4 oacc[2][8] = {};
  float lsumq[2] = {0.f, 0.f};        // per-lane: sum over its s for q = lane&15

  for (int k0 = 0; k0 < 2048; k0 += 64) {
    __syncthreads();
#pragma unroll
    for (int i = 0; i < 4; ++i) {                 // K: 64 rows x 16 chunks
      int c = i * 256 + tid;
      int row = c >> 4, cc = c & 15;
      int g = cc ^ (row & 15);
      async16(Kp + (size_t)(k0 + row) * 2048 + g * 8, &Ks[c * 8]);
    }
#pragma unroll
    for (int i = 0; i < 4; ++i) {                 // V: 128 rows x 8 chunks
      int c = i * 256 + tid;
      int row = c >> 3, cc = c & 7;
      int g = cc ^ (row & 7);
      async16(Vp + (size_t)row * 2048 + k0 + g * 8, &Vs[c * 8]);
    }
    __syncthreads();

    // ---- S^T = K Q^T : sacc[st][qt], col=q, row=s ----
    floatx4 sacc[4][2] = {};
#pragma unroll
    for (int ks = 0; ks < 4; ++ks) {
      half8 kf[4];
#pragma unroll
      for (int st = 0; st < 4; ++st) {
        int row = st * 16 + l15;
        int ch = (ks * 4 + l4) ^ l15;             // row & 15 == l15
        kf[st] = *reinterpret_cast<const half8*>(&Ks[row * 128 + ch * 8]);
      }
#pragma unroll
      for (int st = 0; st < 4; ++st)
#pragma unroll
        for (int qt = 0; qt < 2; ++qt)
          sacc[st][qt] = __builtin_amdgcn_mfma_f32_16x16x32_f16(kf[st], qf[qt][ks], sacc[st][qt], 0, 0, 0);
    }

    // ---- p = 2^s; packed b64 Ps write (4 consecutive s per lane) ----
#pragma unroll
    for (int qt = 0; qt < 2; ++qt)
#pragma unroll
      for (int st = 0; st < 4; ++st) {
        float p0 = exp2f(sacc[st][qt][0]);
        float p1 = exp2f(sacc[st][qt][1]);
        float p2 = exp2f(sacc[st][qt][2]);
        float p3 = exp2f(sacc[st][qt][3]);
        lsumq[qt] += (p0 + p1) + (p2 + p3);
        half4 pv;
        pv[0] = (_Float16)p0; pv[1] = (_Float16)p1;
        pv[2] = (_Float16)p2; pv[3] = (_Float16)p3;
        int ch = (st * 2 + (l4 >> 1)) ^ (l15 & 7);
        *reinterpret_cast<half4*>(
            &Ps[(wave * 32 + qt * 16 + l15) * 64 + ch * 8 + (l4 & 1) * 4]) = pv;
      }

    __builtin_amdgcn_s_waitcnt(0xC07F);  // lgkmcnt(0): own-wave ds_write->ds_read

    // ---- O += P V  (V stored (d,s): NT GEMM) ----
#pragma unroll
    for (int ks2 = 0; ks2 < 2; ++ks2) {
      half8 pf[2];
#pragma unroll
      for (int mt = 0; mt < 2; ++mt)
        pf[mt] = *reinterpret_cast<const half8*>(
            &Ps[(wave * 32 + mt * 16 + l15) * 64 + (((ks2 * 4 + l4) ^ (l15 & 7)) * 8)]);
#pragma unroll
      for (int nt2 = 0; nt2 < 8; ++nt2) {
        int row = nt2 * 16 + l15;
        int ch = (ks2 * 4 + l4) ^ (row & 7);
        half8 vf = *reinterpret_cast<const half8*>(&Vs[row * 64 + ch * 8]);
#pragma unroll
        for (int mt = 0; mt < 2; ++mt)
          oacc[mt][nt2] = __builtin_amdgcn_mfma_f32_16x16x32_f16(pf[mt], vf, oacc[mt][nt2], 0, 0, 0);
      }
    }
  }

#pragma unroll
  for (int qt = 0; qt < 2; ++qt) {
    lsumq[qt] += __shfl_xor(lsumq[qt], 16);
    lsumq[qt] += __shfl_xor(lsumq[qt], 32);
  }

  _Float16* Op = O + ((size_t)(b * 2048 + q0 + wave * 32)) * 2048 + h * 128;
#pragma unroll
  for (int mt = 0; mt < 2; ++mt)
#pragma unroll
    for (int r = 0; r < 4; ++r) {
      float inv = 1.0f / __shfl(lsumq[mt], l4 * 4 + r);
#pragma unroll
      for (int nt2 = 0; nt2 < 8; ++nt2) {
        int row = mt * 16 + l4 * 4 + r;
        int col = nt2 * 16 + l15;
        Op[(size_t)row * 2048 + col] = (_Float16)(oacc[mt][nt2][r] * inv);
      }
    }
}

// ---------------------------------------------------------------------------
extern "C" void kernel_launch(void* const* d_in, const int* in_sizes, int n_in,
                              void* d_out, int out_size, void* d_ws, size_t ws_size,
                              hipStream_t stream) {
  const float* x = (const float*)d_in[0];
  const float* wq = (const float*)d_in[1];
  const float* wk = (const float*)d_in[2];
  const float* wv = (const float*)d_in[3];
  const float* wo = (const float*)d_in[4];
  float* out = (float*)d_out;

  const size_t XN = (size_t)4096 * 2048;
  const size_t WN = (size_t)2048 * 2048;
  _Float16* xh = (_Float16*)d_ws;
  _Float16* qh = xh + XN;          // Q then K contiguous (row-major, ld 2048)
  _Float16* vth = xh + 3 * XN;     // per-batch transposed V
  _Float16* oh = xh + 4 * XN;
  _Float16* wqh = xh + 5 * XN;     // wq,wk,wv,wo contiguous

  const float SM_SCALE = 0.08838834764831845f * 1.4426950408889634f;

  cvt_all<<<dim3(24576), 256, 0, stream>>>(x, wq, wk, wv, wo, xh, wqh, SM_SCALE);
  gemm_nt<0><<<dim3(48, 16), 512, 0, stream>>>(xh, wqh, qh, vth);
  flash_attn<<<dim3(16, 32), 256, 0, stream>>>(qh, qh + XN, vth, oh);
  gemm_nt<2><<<dim3(16, 16), 512, 0, stream>>>(oh, wqh + 3 * WN, out, nullptr);
}

// Round 2
// 403.250 us; speedup vs baseline: 1.0145x; 1.0145x over previous
//
#include <hip/hip_runtime.h>

// ---------------------------------------------------------------------------
// Fused MHA block on MI355X (gfx950). fp16 MFMA 16x16x32, fp32 accum.
// Round-9:
//  * gemm_nt re-ported to the m201 geometry: 256x256 tile, BK=64, 512 thr,
//    8 waves (2M x 4N), wave tile 128x64 -> 16 MFMA per phase (round-8 had 8,
//    too little to cover HBM latency -> VALUBusy 13%). Strided wave mapping
//    (A row = mt*32+wm*16+l15, B row = nt*64+wn*16+l15) so each phase reads a
//    contiguous tile-half for ALL waves; stage-halves == read-phases (fixes
//    round-8's cross-wave A-half aliasing). Counted vmcnt moved AFTER the
//    MFMA cluster: uniform vmcnt(6) (8 outstanding, retire 2/phase, 3.75-
//    phase slack ~600cy); peeled last tile drains 4/2/0. XCD swizzle now
//    bn-fastest chunked (2 bm-rows per XCD -> A stays L2-hot; round-8's
//    bm-fastest doubled FETCH_SIZE). LDS 128 KiB, 1 block/CU.
//  * flash_attn / cvt_all unchanged (round-7 verified).
// ---------------------------------------------------------------------------

typedef _Float16 half8 __attribute__((ext_vector_type(8)));
typedef _Float16 half4 __attribute__((ext_vector_type(4)));
typedef float floatx4 __attribute__((ext_vector_type(4)));

__device__ __forceinline__ void async16(const void* g, void* l) {
  __builtin_amdgcn_global_load_lds((__attribute__((address_space(1))) void*)(g),
                                   (__attribute__((address_space(3))) void*)(l),
                                   16, 0, 0);
}

// ---- fp32 -> fp16 convert: x (2^21 quads) then 4 weights (2^20 each) -------
__global__ void cvt_all(const float* __restrict__ x, const float* __restrict__ w0,
                        const float* __restrict__ w1, const float* __restrict__ w2,
                        const float* __restrict__ w3, _Float16* __restrict__ xh,
                        _Float16* __restrict__ wh, float scale0) {
  int i = blockIdx.x * blockDim.x + threadIdx.x;
  const int XQ = 1 << 21;
  float sc = 1.0f;
  const float* src;
  _Float16* dst;
  int j;
  if (i < XQ) { src = x; dst = xh; j = i; }
  else {
    int t = i - XQ;
    int m = t >> 20;
    src = (m == 0) ? w0 : (m == 1) ? w1 : (m == 2) ? w2 : w3;
    if (m == 0) sc = scale0;
    dst = wh; j = t;
  }
  int js = (i < XQ) ? j : (j & ((1 << 20) - 1));
  float4 v = reinterpret_cast<const float4*>(src)[js];
  union { _Float16 h[4]; short4 s; } u;
  u.h[0] = (_Float16)(v.x * sc); u.h[1] = (_Float16)(v.y * sc);
  u.h[2] = (_Float16)(v.z * sc); u.h[3] = (_Float16)(v.w * sc);
  reinterpret_cast<short4*>(dst)[j] = u.s;
}

// ---- pipelined NT GEMM helpers ---------------------------------------------
__device__ __forceinline__ void rdA4(half8 (&f)[4][2], const _Float16* base,
                                     int ch0, int ch1) {
#pragma unroll
  for (int mt = 0; mt < 4; ++mt) {
    f[mt][0] = *reinterpret_cast<const half8*>(base + mt * 2048 + ch0);
    f[mt][1] = *reinterpret_cast<const half8*>(base + mt * 2048 + ch1);
  }
}
__device__ __forceinline__ void rdB2(half8 (&f)[2][2], const _Float16* base,
                                     int ch0, int ch1) {
#pragma unroll
  for (int nt = 0; nt < 2; ++nt) {
    f[nt][0] = *reinterpret_cast<const half8*>(base + nt * 4096 + ch0);
    f[nt][1] = *reinterpret_cast<const half8*>(base + nt * 4096 + ch1);
  }
}
template <int MO, int NO>
__device__ __forceinline__ void mmg16(floatx4 (&acc)[8][4], const half8 (&af)[4][2],
                                      const half8 (&bf)[2][2]) {
#pragma unroll
  for (int kk = 0; kk < 2; ++kk)
#pragma unroll
    for (int mt = 0; mt < 4; ++mt)
#pragma unroll
      for (int nt = 0; nt < 2; ++nt)
        acc[MO + mt][NO + nt] = __builtin_amdgcn_mfma_f32_16x16x32_f16(
            af[mt][kk], bf[nt][kk], acc[MO + mt][NO + nt], 0, 0, 0);
}

// ---- NT GEMM (16x16x32): C[m][n] = sum_k A[m][k]*Bw[n][k] ------------------
// 256x256 tile, 512 threads, 8 waves 2Mx4N, wave tile 128x64 (strided).
// OUT_MODE 0: fused QKV epilogue; OUT_MODE 2: fp32 row-major. NBN = N/256.
template <int OUT_MODE, int NBN>
__global__ __launch_bounds__(512, 2)
void gemm_nt(const _Float16* __restrict__ A, const _Float16* __restrict__ Bw,
             void* __restrict__ Cv, void* __restrict__ Cv2) {
  __shared__ _Float16 As[2][256 * 64];
  __shared__ _Float16 Bs[2][256 * 64];
  const int tid = threadIdx.x;
  const int wave = tid >> 6, lane = tid & 63;
  const int wm = wave >> 2, wn = wave & 3;      // 2M x 4N wave grid
  const int l15 = lane & 15, l4 = lane >> 4;

  // XCD swizzle, bn-fastest chunks: each XCD gets 2 bm-rows (A L2-resident).
  const int nwg = NBN * 16;                     // 384 or 128, both %8==0
  const int orig = blockIdx.x;
  const int swz = (orig & 7) * (nwg >> 3) + (orig >> 3);
  const int bn = swz % NBN, bm = swz / NBN;

  // Staging: xor-swizzled global source, linear LDS dest. Round j = 64 rows.
  const int srow = tid >> 3;
  const int g = (tid & 7) ^ (srow & 7);
  const _Float16* ags = A + (size_t)(bm * 256 + srow) * 2048 + g * 8;
  const _Float16* bgs = Bw + (size_t)(bn * 256 + srow) * 2048 + g * 8;
  const int ldst = tid * 8;

  // Fragment coords. A row = mt*32 + wm*16 + l15; B row = nt*64 + wn*16 + l15.
  const int arow = wm * 16 + l15;
  const int brow = wn * 16 + l15;
  const int ch0 = (l4 ^ (l15 & 7)) * 8;
  const int ch1 = ((l4 + 4) ^ (l15 & 7)) * 8;

  // Prologue: stage tile 0 (A j0..3, B j0..3), one-time full drain.
#pragma unroll
  for (int j = 0; j < 4; ++j) {
    async16(ags + (size_t)j * 131072, &As[0][j * 4096 + ldst]);
    async16(bgs + (size_t)j * 131072, &Bs[0][j * 4096 + ldst]);
  }
  asm volatile("s_waitcnt vmcnt(0)" ::: "memory");
  __builtin_amdgcn_s_barrier();

  floatx4 acc[8][4] = {};
  half8 afA[4][2], afB[4][2], bfA[2][2], bfB[2][2];

  for (int t = 0; t < 31; ++t) {
    const int cur = t & 1, nxt = cur ^ 1;
    const int kn = t * 64 + 64;
    const _Float16* Ab = &As[cur][arow * 64];
    const _Float16* Bb = &Bs[cur][brow * 64];
    _Float16* Asn = &As[nxt][ldst];
    _Float16* Bsn = &Bs[nxt][ldst];

    // -- phase 0: read A-h0[t]; stage A-h0[t+1]; MFMA leftover Q11 of t-1
    rdA4(afA, Ab, ch0, ch1);
    async16(ags + kn, Asn);
    async16(ags + 131072 + kn, Asn + 4096);
    __builtin_amdgcn_s_barrier();
    __builtin_amdgcn_s_waitcnt(0xC07F);   // lgkmcnt(0)
    __builtin_amdgcn_s_setprio(1);
    if (t) mmg16<4, 2>(acc, afB, bfB);
    __builtin_amdgcn_s_setprio(0);
    asm volatile("s_waitcnt vmcnt(6)" ::: "memory");
    __builtin_amdgcn_s_barrier();

    // -- phase 1: read B-h0[t]; stage B-h0[t+1]; MFMA Q00
    rdB2(bfA, Bb, ch0, ch1);
    async16(bgs + kn, Bsn);
    async16(bgs + 131072 + kn, Bsn + 4096);
    __builtin_amdgcn_s_barrier();
    __builtin_amdgcn_s_waitcnt(0xC07F);
    __builtin_amdgcn_s_setprio(1);
    mmg16<0, 0>(acc, afA, bfA);
    __builtin_amdgcn_s_setprio(0);
    asm volatile("s_waitcnt vmcnt(6)" ::: "memory");
    __builtin_amdgcn_s_barrier();

    // -- phase 2: read B-h1[t]; stage B-h1[t+1]; MFMA Q01
    rdB2(bfB, Bb + 8192, ch0, ch1);
    async16(bgs + 262144 + kn, Bsn + 8192);
    async16(bgs + 393216 + kn, Bsn + 12288);
    __builtin_amdgcn_s_barrier();
    __builtin_amdgcn_s_waitcnt(0xC07F);
    __builtin_amdgcn_s_setprio(1);
    mmg16<0, 2>(acc, afA, bfB);
    __builtin_amdgcn_s_setprio(0);
    asm volatile("s_waitcnt vmcnt(6)" ::: "memory");
    __builtin_amdgcn_s_barrier();

    // -- phase 3: read A-h1[t]; stage A-h1[t+1]; MFMA Q10
    rdA4(afB, Ab + 8192, ch0, ch1);
    async16(ags + 262144 + kn, Asn + 8192);
    async16(ags + 393216 + kn, Asn + 12288);
    __builtin_amdgcn_s_barrier();
    __builtin_amdgcn_s_waitcnt(0xC07F);
    __builtin_amdgcn_s_setprio(1);
    mmg16<4, 0>(acc, afB, bfA);
    __builtin_amdgcn_s_setprio(0);
    asm volatile("s_waitcnt vmcnt(6)" ::: "memory");
    __builtin_amdgcn_s_barrier();
  }

  // ---- peeled last tile (t=31, buf 1, no staging): drain 4 -> 2 -> 0 ----
  {
    const _Float16* Ab = &As[1][arow * 64];
    const _Float16* Bb = &Bs[1][brow * 64];
    rdA4(afA, Ab, ch0, ch1);
    mmg16<4, 2>(acc, afB, bfB);           // leftover Q11 of t=30 (regs only)
    asm volatile("s_waitcnt vmcnt(4)" ::: "memory");
    __builtin_amdgcn_s_barrier();
    rdB2(bfA, Bb, ch0, ch1);
    mmg16<0, 0>(acc, afA, bfA);
    asm volatile("s_waitcnt vmcnt(2)" ::: "memory");
    __builtin_amdgcn_s_barrier();
    rdB2(bfB, Bb + 8192, ch0, ch1);
    mmg16<0, 2>(acc, afA, bfB);
    asm volatile("s_waitcnt vmcnt(0)" ::: "memory");
    __builtin_amdgcn_s_barrier();
    rdA4(afB, Ab + 8192, ch0, ch1);
    mmg16<4, 0>(acc, afB, bfA);
    mmg16<4, 2>(acc, afB, bfB);
  }

  // ---- epilogues (row = bm*256 + mt*32 + wm*16 + l4*4 + r,
  //                 col = bn*256 + nt*64 + wn*16 + l15) ----
  const int cb0 = bn * 256;
  if constexpr (OUT_MODE == 0) {
    if (cb0 < 4096) {           // Q or K: row-major fp16, ld 2048
      _Float16* C = (_Float16*)Cv + (size_t)(cb0 >> 11) * (4096ull * 2048);
#pragma unroll
      for (int mt = 0; mt < 8; ++mt)
#pragma unroll
        for (int nt = 0; nt < 4; ++nt) {
          int r0 = bm * 256 + mt * 32 + wm * 16 + l4 * 4;
          int cg = (cb0 + nt * 64 + wn * 16 + l15) & 2047;
#pragma unroll
          for (int r = 0; r < 4; ++r)
            C[(size_t)(r0 + r) * 2048 + cg] = (_Float16)acc[mt][nt][r];
        }
    } else {                    // V: per-batch transposed [b][d][s]
      _Float16* C = (_Float16*)Cv2;
#pragma unroll
      for (int mt = 0; mt < 8; ++mt)
#pragma unroll
        for (int nt = 0; nt < 4; ++nt) {
          int m0 = bm * 256 + mt * 32 + wm * 16 + l4 * 4;
          int d = cb0 + nt * 64 + wn * 16 + l15 - 4096;
          size_t base = (size_t)(m0 >> 11) * (2048ull * 2048) + (size_t)d * 2048 + (m0 & 2047);
          union { _Float16 h[4]; short4 s; } u;
#pragma unroll
          for (int r = 0; r < 4; ++r) u.h[r] = (_Float16)acc[mt][nt][r];
          *reinterpret_cast<short4*>(C + base) = u.s;
        }
    }
  } else {
    float* C = (float*)Cv;
#pragma unroll
    for (int mt = 0; mt < 8; ++mt)
#pragma unroll
      for (int nt = 0; nt < 4; ++nt) {
        int r0 = bm * 256 + mt * 32 + wm * 16 + l4 * 4;
        int cg = cb0 + nt * 64 + wn * 16 + l15;
#pragma unroll
        for (int r = 0; r < 4; ++r)
          C[(size_t)(r0 + r) * 2048 + cg] = acc[mt][nt][r];
      }
  }
}

// ---- Flash attention (unchanged, round-7 verified) --------------------------
// grid = (16 q-tiles of 128, 32 b*h); block = 256 (4 waves x 32 q rows).
__global__ __launch_bounds__(256, 2)
void flash_attn(const _Float16* __restrict__ Q, const _Float16* __restrict__ Kg,
                const _Float16* __restrict__ Vt, _Float16* __restrict__ O) {
  __shared__ _Float16 Ks[64 * 128];   // [key][hd], 16-chunk xor swizzle
  __shared__ _Float16 Vs[128 * 64];   // [d][s],    8-chunk xor swizzle
  __shared__ _Float16 Ps[128 * 64];   // [q][key],  8-chunk xor swizzle
  const int tid = threadIdx.x, wave = tid >> 6, lane = tid & 63;
  const int l15 = lane & 15, l4 = lane >> 4;
  const int bh = blockIdx.y, b = bh >> 4, h = bh & 15;
  const int q0 = blockIdx.x * 128;

  const _Float16* Qp = Q + ((size_t)(b * 2048 + q0 + wave * 32)) * 2048 + h * 128;
  const _Float16* Kp = Kg + (size_t)b * 2048 * 2048 + h * 128;
  const _Float16* Vp = Vt + (size_t)b * 2048 * 2048 + (size_t)(h * 128) * 2048;

  half8 qf[2][4];
#pragma unroll
  for (int qt = 0; qt < 2; ++qt)
#pragma unroll
    for (int ks = 0; ks < 4; ++ks)
      qf[qt][ks] = *reinterpret_cast<const half8*>(
          Qp + (size_t)(qt * 16 + l15) * 2048 + ks * 32 + l4 * 8);

  floatx4 oacc[2][8] = {};
  float lsumq[2] = {0.f, 0.f};        // per-lane: sum over its s for q = lane&15

  for (int k0 = 0; k0 < 2048; k0 += 64) {
    __syncthreads();
#pragma unroll
    for (int i = 0; i < 4; ++i) {                 // K: 64 rows x 16 chunks
      int c = i * 256 + tid;
      int row = c >> 4, cc = c & 15;
      int g = cc ^ (row & 15);
      async16(Kp + (size_t)(k0 + row) * 2048 + g * 8, &Ks[c * 8]);
    }
#pragma unroll
    for (int i = 0; i < 4; ++i) {                 // V: 128 rows x 8 chunks
      int c = i * 256 + tid;
      int row = c >> 3, cc = c & 7;
      int g = cc ^ (row & 7);
      async16(Vp + (size_t)row * 2048 + k0 + g * 8, &Vs[c * 8]);
    }
    __syncthreads();

    // ---- S^T = K Q^T : sacc[st][qt], col=q, row=s ----
    floatx4 sacc[4][2] = {};
#pragma unroll
    for (int ks = 0; ks < 4; ++ks) {
      half8 kf[4];
#pragma unroll
      for (int st = 0; st < 4; ++st) {
        int row = st * 16 + l15;
        int ch = (ks * 4 + l4) ^ l15;             // row & 15 == l15
        kf[st] = *reinterpret_cast<const half8*>(&Ks[row * 128 + ch * 8]);
      }
#pragma unroll
      for (int st = 0; st < 4; ++st)
#pragma unroll
        for (int qt = 0; qt < 2; ++qt)
          sacc[st][qt] = __builtin_amdgcn_mfma_f32_16x16x32_f16(kf[st], qf[qt][ks], sacc[st][qt], 0, 0, 0);
    }

    // ---- p = 2^s; packed b64 Ps write (4 consecutive s per lane) ----
#pragma unroll
    for (int qt = 0; qt < 2; ++qt)
#pragma unroll
      for (int st = 0; st < 4; ++st) {
        float p0 = exp2f(sacc[st][qt][0]);
        float p1 = exp2f(sacc[st][qt][1]);
        float p2 = exp2f(sacc[st][qt][2]);
        float p3 = exp2f(sacc[st][qt][3]);
        lsumq[qt] += (p0 + p1) + (p2 + p3);
        half4 pv;
        pv[0] = (_Float16)p0; pv[1] = (_Float16)p1;
        pv[2] = (_Float16)p2; pv[3] = (_Float16)p3;
        int ch = (st * 2 + (l4 >> 1)) ^ (l15 & 7);
        *reinterpret_cast<half4*>(
            &Ps[(wave * 32 + qt * 16 + l15) * 64 + ch * 8 + (l4 & 1) * 4]) = pv;
      }

    __builtin_amdgcn_s_waitcnt(0xC07F);  // lgkmcnt(0): own-wave ds_write->ds_read

    // ---- O += P V  (V stored (d,s): NT GEMM) ----
#pragma unroll
    for (int ks2 = 0; ks2 < 2; ++ks2) {
      half8 pf[2];
#pragma unroll
      for (int mt = 0; mt < 2; ++mt)
        pf[mt] = *reinterpret_cast<const half8*>(
            &Ps[(wave * 32 + mt * 16 + l15) * 64 + (((ks2 * 4 + l4) ^ (l15 & 7)) * 8)]);
#pragma unroll
      for (int nt2 = 0; nt2 < 8; ++nt2) {
        int row = nt2 * 16 + l15;
        int ch = (ks2 * 4 + l4) ^ (row & 7);
        half8 vf = *reinterpret_cast<const half8*>(&Vs[row * 64 + ch * 8]);
#pragma unroll
        for (int mt = 0; mt < 2; ++mt)
          oacc[mt][nt2] = __builtin_amdgcn_mfma_f32_16x16x32_f16(pf[mt], vf, oacc[mt][nt2], 0, 0, 0);
      }
    }
  }

#pragma unroll
  for (int qt = 0; qt < 2; ++qt) {
    lsumq[qt] += __shfl_xor(lsumq[qt], 16);
    lsumq[qt] += __shfl_xor(lsumq[qt], 32);
  }

  _Float16* Op = O + ((size_t)(b * 2048 + q0 + wave * 32)) * 2048 + h * 128;
#pragma unroll
  for (int mt = 0; mt < 2; ++mt)
#pragma unroll
    for (int r = 0; r < 4; ++r) {
      float inv = 1.0f / __shfl(lsumq[mt], l4 * 4 + r);
#pragma unroll
      for (int nt2 = 0; nt2 < 8; ++nt2) {
        int row = mt * 16 + l4 * 4 + r;
        int col = nt2 * 16 + l15;
        Op[(size_t)row * 2048 + col] = (_Float16)(oacc[mt][nt2][r] * inv);
      }
    }
}

// ---------------------------------------------------------------------------
extern "C" void kernel_launch(void* const* d_in, const int* in_sizes, int n_in,
                              void* d_out, int out_size, void* d_ws, size_t ws_size,
                              hipStream_t stream) {
  const float* x = (const float*)d_in[0];
  const float* wq = (const float*)d_in[1];
  const float* wk = (const float*)d_in[2];
  const float* wv = (const float*)d_in[3];
  const float* wo = (const float*)d_in[4];
  float* out = (float*)d_out;

  const size_t XN = (size_t)4096 * 2048;
  const size_t WN = (size_t)2048 * 2048;
  _Float16* xh = (_Float16*)d_ws;
  _Float16* qh = xh + XN;          // Q then K contiguous (row-major, ld 2048)
  _Float16* vth = xh + 3 * XN;     // per-batch transposed V
  _Float16* oh = xh + 4 * XN;
  _Float16* wqh = xh + 5 * XN;     // wq,wk,wv,wo contiguous

  const float SM_SCALE = 0.08838834764831845f * 1.4426950408889634f;

  cvt_all<<<dim3(24576), 256, 0, stream>>>(x, wq, wk, wv, wo, xh, wqh, SM_SCALE);
  gemm_nt<0, 24><<<dim3(384), 512, 0, stream>>>(xh, wqh, qh, vth);
  flash_attn<<<dim3(16, 32), 256, 0, stream>>>(qh, qh + XN, vth, oh);
  gemm_nt<2, 8><<<dim3(128), 512, 0, stream>>>(oh, wqh + 3 * WN, out, nullptr);
}